// Round 11
// baseline (379.908 us; speedup 1.0000x reference)
//
#include <hip/hip_runtime.h>
#include <hip/hip_bf16.h>
#include <cstdint>
#include <cstddef>

typedef unsigned short u16;
typedef __bf16 bf16x8 __attribute__((ext_vector_type(8)));
typedef float f32x4 __attribute__((ext_vector_type(4)));

#define B_ROWS 4096
#define N_HIDDEN 2048
#define DT_RANK 128

static __device__ __forceinline__ u16 f2bf(float f) {
  unsigned u = __float_as_uint(f);
  u += 0x7FFFu + ((u >> 16) & 1u);   // RTNE
  return (u16)(u >> 16);
}
static __device__ __forceinline__ float bf2f(u16 b) {
  return __uint_as_float(((unsigned)b) << 16);
}
static __device__ __forceinline__ float siluf(float v) {
  return v / (1.0f + __expf(-v));
}
static __device__ __forceinline__ float softplusf(float v) {
  return v > 15.0f ? v : log1pf(__expf(v));
}
static __device__ __forceinline__ void async16(void* lds, const void* g) {
  __builtin_amdgcn_global_load_lds((const __attribute__((address_space(1))) void*)g,
                                   (__attribute__((address_space(3))) void*)lds, 16, 0, 0);
}

// ---------------- merged f32 -> bf16 convert (all tensors, one launch) ----------------
struct CvtJobs {
  const float* src[8];
  u16* dst[8];
  int rl4[8];      // row length in float4 units
  int dstride[8];  // dst row stride in u16 units
  int cum[9];      // cumulative row counts
};
__global__ __launch_bounds__(256)
void cvt_all_kernel(CvtJobs J) {
  int b = blockIdx.x;
  int job = 0;
#pragma unroll
  for (int k = 1; k < 8; ++k) if (b >= J.cum[k]) job = k;
  const int row = b - J.cum[job];
  const int rl4 = J.rl4[job];
  const float4* s = (const float4*)(J.src[job] + (size_t)row * (rl4 * 4));
  ushort4* d = (ushort4*)(J.dst[job] + (size_t)row * J.dstride[job]);
  for (int c = threadIdx.x; c < rl4; c += blockDim.x) {
    float4 f = s[c];
    ushort4 o;
    o.x = f2bf(f.x); o.y = f2bf(f.y); o.z = f2bf(f.z); o.w = f2bf(f.w);
    d[c] = o;
  }
}

// ================= 256x256 GEMM: single-gate deep pipeline, unrolled buffers =============
// (r10 structure, unchanged — see its ledger. Rect-XCD tiling, quadrant phases,
//  single vmcnt(6) gate per K-tile, literal LDS buffer offsets via unroll-2.)
template <int NN, int KK, int LDA, int LDB, int EPI, int GX, int GY, int RH, int RW>
__global__ __launch_bounds__(512, 1)
void gemm8(const u16* __restrict__ A, const u16* __restrict__ Bw,
           float* __restrict__ outf, u16* __restrict__ outb, long long zstride)
{
  extern __shared__ u16 lds[];
  u16* ldsA = lds;            // 4 slots (buf*2+half) * 8192 u16 = 64 KiB
  u16* ldsB = lds + 32768;    // 64 KiB
  constexpr int NT = KK / 64;
  static_assert(NT >= 4 && (NT % 2) == 0, "schedule assumes even NT >= 4");
  static_assert(GX * GY == 8 * RH * RW, "rect must partition grid over 8 XCDs");
  static_assert(GX % RW == 0 && GY % RH == 0, "rect divides grid");
  constexpr int XCOLS = GX / RW;
  static_assert((GY / RH) * XCOLS == 8, "XCD grid must be 8");

  const int t = threadIdx.x;
  const int lane = t & 63, w = t >> 6;
  const int wr = w >> 2, wc = w & 3;      // wave grid 2M x 4N
  const int r = lane & 15;
  const int q4 = lane >> 4;               // 0..3 (k-quad)

  // ---- rect-XCD tile mapping (bijective; locality-only) ----
  const int bid = blockIdx.y * GX + blockIdx.x;
  const int xcd = bid & 7;
  const int i = bid >> 3;                 // 0..RH*RW-1
  const int xr = xcd / XCOLS, xc = xcd % XCOLS;
  const int m0 = (xr * RH + i / RW) * 256;
  const int n0 = (xc * RW + i % RW) * 256;
  const int koff = blockIdx.z * KK;

  f32x4 acc[2][2][4][2] = {};   // [a][b][fi][g]

  auto stA = [&](int buf, int half, int k0) {
#pragma unroll
    for (int i2 = 0; i2 < 2; ++i2) {
      const int ii = w * 2 + i2;
      const int c = ii * 64 + lane;          // 16B-chunk index in half-tile
      const int row = c >> 3;
      const int ch = (c & 7) ^ (row & 7);    // inverse-swizzled global chunk
      async16(ldsA + (buf * 2 + half) * 8192 + ii * 512,
              A + (size_t)(m0 + half * 128 + row) * LDA + (koff + k0 + ch * 8));
    }
  };
  auto stB = [&](int buf, int half, int k0) {
#pragma unroll
    for (int i2 = 0; i2 < 2; ++i2) {
      const int ii = w * 2 + i2;
      const int c = ii * 64 + lane;
      const int row = c >> 3;
      const int ch = (c & 7) ^ (row & 7);
      async16(ldsB + (buf * 2 + half) * 8192 + ii * 512,
              Bw + (size_t)(n0 + half * 128 + row) * LDB + (koff + k0 + ch * 8));
    }
  };

  // per-lane ds_read base pointers; all reads are base + compile-time offset
  const int rb = r & 7;
  const int s0 = (q4 ^ rb) << 3;                // u16 units, K32-slice 0
  const int s1 = ((4 + q4) ^ rb) << 3;          // K32-slice 1
  const u16* baA0 = ldsA + (wr * 64 + r) * 64 + s0;
  const u16* baA1 = ldsA + (wr * 64 + r) * 64 + s1;
  const u16* baB0 = ldsB + (wc * 32 + r) * 64 + s0;
  const u16* baB1 = ldsB + (wc * 32 + r) * 64 + s1;

  // ---- prologue: tile0 A0,B0,B1,A1 + tile1 A0,B0,B1 ; vmcnt(6) -> tile0 resident
  stA(0, 0, 0); stB(0, 0, 0); stB(0, 1, 0); stA(0, 1, 0);
  stA(1, 0, 64); stB(1, 0, 64); stB(1, 1, 64);
  asm volatile("s_waitcnt vmcnt(6)" ::: "memory");
  __builtin_amdgcn_s_barrier();
  asm volatile("" ::: "memory");

  for (int j0 = 0; j0 < NT; j0 += 2) {
#pragma unroll
    for (int u = 0; u < 2; ++u) {
      const int j = j0 + u;        // buf(j) == u  (j0 even)
      constexpr int SL = 8192;     // u16 per half-slot
      const int CB = u * 2 * SL;   // cur base offset (literal after unroll)
      bf16x8 fa[8], fah[8], fb0v[4], fb1v[4];

      // ======== q0: read fa<-A0(cur) 8, fb0<-B0(cur) 4 ; stage A1(j+1)->nxt ; MFMA Q00
#pragma unroll
      for (int fi = 0; fi < 4; ++fi) {
        fa[fi * 2 + 0] = *(const bf16x8*)(baA0 + CB + fi * 1024);
        fa[fi * 2 + 1] = *(const bf16x8*)(baA1 + CB + fi * 1024);
      }
#pragma unroll
      for (int g = 0; g < 2; ++g) {
        fb0v[g * 2 + 0] = *(const bf16x8*)(baB0 + CB + g * 1024);
        fb0v[g * 2 + 1] = *(const bf16x8*)(baB1 + CB + g * 1024);
      }
      if (j + 1 < NT) stA(u ^ 1, 1, (j + 1) * 64);
      asm volatile("" ::: "memory");
      __builtin_amdgcn_s_barrier();
      asm volatile("s_waitcnt lgkmcnt(0)" ::: "memory");
      __builtin_amdgcn_s_setprio(1);
#pragma unroll
      for (int fi = 0; fi < 4; ++fi)
#pragma unroll
        for (int g = 0; g < 2; ++g) {
          acc[0][0][fi][g] = __builtin_amdgcn_mfma_f32_16x16x32_bf16(fa[fi * 2 + 0], fb0v[g * 2 + 0], acc[0][0][fi][g], 0, 0, 0);
          acc[0][0][fi][g] = __builtin_amdgcn_mfma_f32_16x16x32_bf16(fa[fi * 2 + 1], fb0v[g * 2 + 1], acc[0][0][fi][g], 0, 0, 0);
        }
      __builtin_amdgcn_s_setprio(0);
      asm volatile("" ::: "memory");
      __builtin_amdgcn_s_barrier();
      asm volatile("" ::: "memory");

      // ======== q1: read fb1<-B1(cur) 4 ; stage A0(j+2)->cur ; MFMA Q01
#pragma unroll
      for (int g = 0; g < 2; ++g) {
        fb1v[g * 2 + 0] = *(const bf16x8*)(baB0 + CB + SL + g * 1024);
        fb1v[g * 2 + 1] = *(const bf16x8*)(baB1 + CB + SL + g * 1024);
      }
      if (j + 2 < NT) stA(u, 0, (j + 2) * 64);
      asm volatile("" ::: "memory");
      __builtin_amdgcn_s_barrier();
      asm volatile("s_waitcnt lgkmcnt(0)" ::: "memory");
      __builtin_amdgcn_s_setprio(1);
#pragma unroll
      for (int fi = 0; fi < 4; ++fi)
#pragma unroll
        for (int g = 0; g < 2; ++g) {
          acc[0][1][fi][g] = __builtin_amdgcn_mfma_f32_16x16x32_bf16(fa[fi * 2 + 0], fb1v[g * 2 + 0], acc[0][1][fi][g], 0, 0, 0);
          acc[0][1][fi][g] = __builtin_amdgcn_mfma_f32_16x16x32_bf16(fa[fi * 2 + 1], fb1v[g * 2 + 1], acc[0][1][fi][g], 0, 0, 0);
        }
      __builtin_amdgcn_s_setprio(0);
      asm volatile("" ::: "memory");
      __builtin_amdgcn_s_barrier();
      asm volatile("" ::: "memory");

      // ======== q2: read fah<-A1(cur) 8 ; stage B0(j+2)->cur ; MFMA Q10
#pragma unroll
      for (int fi = 0; fi < 4; ++fi) {
        fah[fi * 2 + 0] = *(const bf16x8*)(baA0 + CB + SL + fi * 1024);
        fah[fi * 2 + 1] = *(const bf16x8*)(baA1 + CB + SL + fi * 1024);
      }
      if (j + 2 < NT) stB(u, 0, (j + 2) * 64);
      asm volatile("" ::: "memory");
      __builtin_amdgcn_s_barrier();
      asm volatile("s_waitcnt lgkmcnt(0)" ::: "memory");
      __builtin_amdgcn_s_setprio(1);
#pragma unroll
      for (int fi = 0; fi < 4; ++fi)
#pragma unroll
        for (int g = 0; g < 2; ++g) {
          acc[1][0][fi][g] = __builtin_amdgcn_mfma_f32_16x16x32_bf16(fah[fi * 2 + 0], fb0v[g * 2 + 0], acc[1][0][fi][g], 0, 0, 0);
          acc[1][0][fi][g] = __builtin_amdgcn_mfma_f32_16x16x32_bf16(fah[fi * 2 + 1], fb0v[g * 2 + 1], acc[1][0][fi][g], 0, 0, 0);
        }
      __builtin_amdgcn_s_setprio(0);
      asm volatile("" ::: "memory");
      __builtin_amdgcn_s_barrier();
      asm volatile("" ::: "memory");

      // ======== q3: no reads ; stage B1(j+2)->cur ; MFMA Q11 ; SINGLE GATE ; barrier
      if (j + 2 < NT) stB(u, 1, (j + 2) * 64);
      asm volatile("" ::: "memory");
      __builtin_amdgcn_s_barrier();
      __builtin_amdgcn_s_setprio(1);
#pragma unroll
      for (int fi = 0; fi < 4; ++fi)
#pragma unroll
        for (int g = 0; g < 2; ++g) {
          acc[1][1][fi][g] = __builtin_amdgcn_mfma_f32_16x16x32_bf16(fah[fi * 2 + 0], fb1v[g * 2 + 0], acc[1][1][fi][g], 0, 0, 0);
          acc[1][1][fi][g] = __builtin_amdgcn_mfma_f32_16x16x32_bf16(fah[fi * 2 + 1], fb1v[g * 2 + 1], acc[1][1][fi][g], 0, 0, 0);
        }
      __builtin_amdgcn_s_setprio(0);
      if (j + 2 < NT)      { asm volatile("s_waitcnt vmcnt(6)" ::: "memory"); }
      else if (j + 1 < NT) { asm volatile("s_waitcnt vmcnt(0)" ::: "memory"); }
      asm volatile("" ::: "memory");
      __builtin_amdgcn_s_barrier();
      asm volatile("" ::: "memory");
    }
  }

  // ---- epilogue: C/D 16x16 layout col=lane&15, row=(lane>>4)*4+reg
  float* of = outf ? (outf + (size_t)blockIdx.z * zstride) : nullptr;
#pragma unroll
  for (int a = 0; a < 2; ++a)
#pragma unroll
    for (int b = 0; b < 2; ++b)
#pragma unroll
      for (int fi = 0; fi < 4; ++fi)
#pragma unroll
        for (int g = 0; g < 2; ++g)
#pragma unroll
          for (int tt = 0; tt < 4; ++tt) {
            const int grow = m0 + a * 128 + wr * 64 + fi * 16 + q4 * 4 + tt;
            const int gcol = n0 + b * 128 + wc * 32 + g * 16 + r;
            const float v = acc[a][b][fi][g][tt];
            if constexpr (EPI == 0) {
              outb[(size_t)grow * NN + gcol] = f2bf(siluf(v));
            } else {
              of[(size_t)grow * NN + gcol] = v;
            }
          }
}

// ---------------- 128x128 2-phase GEMM (K=128 y-GEMM, vectorized epilogue) ----------------
// EPI=2 epilogue: acc -> LDS f32 image (stride 132, 2-way writes / 4-way reads, both cheap),
// barrier, then each thread owns row t>>1, cols (t&1)*64..+63 -> ushort4-vectorized
// xaux/saux loads and outb stores (full-line coalescing vs old 2B scatter).
template <int NN, int KK, int LDA, int EPI>
__global__ __launch_bounds__(256)
void gemm_bt(const u16* __restrict__ A, const u16* __restrict__ Bw,
             float* __restrict__ outf, u16* __restrict__ outb,
             const float* __restrict__ aux1, const float* __restrict__ aux2,
             const float* __restrict__ aux3,
             const u16* __restrict__ xaux, const u16* __restrict__ saux)
{
  constexpr int BM = 128, BK = 64;
  extern __shared__ u16 sm[];
  u16* As = sm;                 // [2][BM*BK] = 16384 u16
  u16* Bs = sm + 2 * BM * BK;   // [2][BM*BK]
  const int t = threadIdx.x;
  const int lane = t & 63, w = t >> 6;
  const int m0 = blockIdx.y * BM, n0 = blockIdx.x * BM;
  const int mw = (w >> 1) * 64, nw = (w & 1) * 64;
  const int r = lane & 15;
  const int kq = (lane >> 4) * 8;

  f32x4 acc[4][4] = {};

  auto stage = [&](int buf, int k0) {
#pragma unroll
    for (int i = 0; i < 4; ++i) {
      const int slot0 = (w * 4 + i) * 64;
      const int s = slot0 + lane;
      const int row = s >> 3, cs = (s & 7) * 8;
      async16(As + buf * BM * BK + slot0 * 8, A + (size_t)(m0 + row) * LDA + k0 + cs);
      async16(Bs + buf * BM * BK + slot0 * 8, Bw + (size_t)(n0 + row) * KK + k0 + cs);
    }
  };

  stage(0, 0);
  asm volatile("s_waitcnt vmcnt(0)" ::: "memory");
  __syncthreads();
  int cur = 0;

  for (int k0 = 0; k0 < KK; k0 += BK) {
    if (k0 + BK < KK) stage(cur ^ 1, k0 + BK);
#pragma unroll
    for (int kk = 0; kk < BK; kk += 32) {
      bf16x8 af[4], bb[4];
#pragma unroll
      for (int f = 0; f < 4; ++f)
        af[f] = *(const bf16x8*)(As + cur * BM * BK + (mw + f * 16 + r) * BK + kk + kq);
#pragma unroll
      for (int f = 0; f < 4; ++f)
        bb[f] = *(const bf16x8*)(Bs + cur * BM * BK + (nw + f * 16 + r) * BK + kk + kq);
#pragma unroll
      for (int fm = 0; fm < 4; ++fm)
#pragma unroll
        for (int fn = 0; fn < 4; ++fn)
          acc[fm][fn] = __builtin_amdgcn_mfma_f32_16x16x32_bf16(af[fm], bb[fn], acc[fm][fn], 0, 0, 0);
    }
    asm volatile("s_waitcnt vmcnt(0)" ::: "memory");
    __syncthreads();
    cur ^= 1;
  }

  const int rr = (lane >> 4) * 4;
  const int cc = lane & 15;
  if constexpr (EPI == 2) {
    // transpose acc through LDS (all K-loop LDS reads retired by the final barrier)
    float* fs = (float*)sm;     // 128 x (stride 132) f32 = 67584 B
#pragma unroll
    for (int fm = 0; fm < 4; ++fm)
#pragma unroll
      for (int fn = 0; fn < 4; ++fn)
#pragma unroll
        for (int tt = 0; tt < 4; ++tt)
          fs[(mw + fm * 16 + rr + tt) * 132 + (nw + fn * 16 + cc)] = acc[fm][fn][tt];
    __syncthreads();
    const int lr2 = t >> 1;
    const int c0 = (t & 1) * 64;
    const size_t grow = (size_t)(m0 + lr2);
    const float bcv = aux2[grow];
    const u16* xr = xaux + grow * NN + n0 + c0;
    const u16* sr = saux + grow * NN + n0 + c0;
    u16* orow = outb + grow * NN + n0 + c0;
#pragma unroll
    for (int c8 = 0; c8 < 64; c8 += 8) {
      const int col = n0 + c0 + c8;
      float4 va = *(const float4*)&fs[lr2 * 132 + c0 + c8];
      float4 vb = *(const float4*)&fs[lr2 * 132 + c0 + c8 + 4];
      float4 bda = *(const float4*)&aux1[col];
      float4 bdb = *(const float4*)&aux1[col + 4];
      float4 Da  = *(const float4*)&aux3[col];
      float4 Db  = *(const float4*)&aux3[col + 4];
      ushort4 xa = *(const ushort4*)(xr + c8);
      ushort4 xb = *(const ushort4*)(xr + c8 + 4);
      ushort4 sa = *(const ushort4*)(sr + c8);
      ushort4 sb = *(const ushort4*)(sr + c8 + 4);
      ushort4 o0, o1;
      o0.x = f2bf(bf2f(xa.x) * (softplusf(va.x + bda.x) * bcv + Da.x) * bf2f(sa.x));
      o0.y = f2bf(bf2f(xa.y) * (softplusf(va.y + bda.y) * bcv + Da.y) * bf2f(sa.y));
      o0.z = f2bf(bf2f(xa.z) * (softplusf(va.z + bda.z) * bcv + Da.z) * bf2f(sa.z));
      o0.w = f2bf(bf2f(xa.w) * (softplusf(va.w + bda.w) * bcv + Da.w) * bf2f(sa.w));
      o1.x = f2bf(bf2f(xb.x) * (softplusf(vb.x + bdb.x) * bcv + Db.x) * bf2f(sb.x));
      o1.y = f2bf(bf2f(xb.y) * (softplusf(vb.y + bdb.y) * bcv + Db.y) * bf2f(sb.y));
      o1.z = f2bf(bf2f(xb.z) * (softplusf(vb.z + bdb.z) * bcv + Db.z) * bf2f(sb.z));
      o1.w = f2bf(bf2f(xb.w) * (softplusf(vb.w + bdb.w) * bcv + Db.w) * bf2f(sb.w));
      *(ushort4*)(orow + c8) = o0;
      *(ushort4*)(orow + c8 + 4) = o1;
    }
  } else {
#pragma unroll
    for (int fm = 0; fm < 4; ++fm) {
#pragma unroll
      for (int fn = 0; fn < 4; ++fn) {
#pragma unroll
        for (int tt = 0; tt < 4; ++tt) {
          const int grow = m0 + mw + fm * 16 + rr + tt;
          const int gcol = n0 + nw + fn * 16 + cc;
          outf[(size_t)grow * NN + gcol] = acc[fm][fn][tt];
        }
      }
    }
  }
}

// ---------------- skinny GEMM: part[kz] = xbr @ Wxp^T over K-chunk ----------------
__global__ __launch_bounds__(256)
void gemm_xproj(const u16* __restrict__ A, const u16* __restrict__ Bw,
                float* __restrict__ part)
{
  constexpr int BK = 64;
  __shared__ alignas(16) u16 As[64 * BK];
  __shared__ alignas(16) u16 Bs[160 * BK];
  const int t = threadIdx.x, lane = t & 63, w = t >> 6;
  const int m0 = blockIdx.x * 64;
  const int kz = blockIdx.y;
  const int r = lane & 15, kq = (lane >> 4) * 8;
  f32x4 acc[10] = {};
  for (int kt = 0; kt < 1024; kt += BK) {
    const int k0 = kz * 1024 + kt;
#pragma unroll
    for (int i = 0; i < 2; ++i) {
      const int slot0 = (w * 2 + i) * 64;
      const int s = slot0 + lane;
      async16(As + slot0 * 8, A + (size_t)(m0 + (s >> 3)) * 4096 + k0 + (s & 7) * 8);
    }
#pragma unroll
    for (int i = 0; i < 5; ++i) {
      const int slot0 = (w * 5 + i) * 64;
      const int s = slot0 + lane;
      async16(Bs + slot0 * 8, Bw + (size_t)(s >> 3) * 4096 + k0 + (s & 7) * 8);
    }
    asm volatile("s_waitcnt vmcnt(0)" ::: "memory");
    __syncthreads();
#pragma unroll
    for (int kk = 0; kk < BK; kk += 32) {
      bf16x8 af = *(const bf16x8*)(As + (w * 16 + r) * BK + kk + kq);
#pragma unroll
      for (int fn = 0; fn < 10; ++fn) {
        bf16x8 bb = *(const bf16x8*)(Bs + (fn * 16 + r) * BK + kk + kq);
        acc[fn] = __builtin_amdgcn_mfma_f32_16x16x32_bf16(af, bb, acc[fn], 0, 0, 0);
      }
    }
    __syncthreads();
  }
  float* o = part + (size_t)kz * B_ROWS * 160;
  const int rr = (lane >> 4) * 4, cc = lane & 15;
#pragma unroll
  for (int fn = 0; fn < 10; ++fn)
#pragma unroll
    for (int tt = 0; tt < 4; ++tt)
      o[(size_t)(m0 + w * 16 + rr + tt) * 160 + fn * 16 + cc] = acc[fn][tt];
}

// ---------------- reduce split-K partials -> dt_lo (bf16) + bc ----------------
__global__ __launch_bounds__(192)
void xdbl_reduce(const float* __restrict__ part, u16* __restrict__ dtlo,
                 float* __restrict__ bc)
{
  const int row = blockIdx.x, t = threadIdx.x;
  __shared__ float cvals[32];
  float v = 0.0f;
  if (t < 160) {
    const float* p = part + (size_t)row * 160 + t;
#pragma unroll
    for (int z = 0; z < 4; ++z) v += p[(size_t)z * B_ROWS * 160];
  }
  if (t < DT_RANK) dtlo[(size_t)row * DT_RANK + t] = f2bf(v);
  if (t >= DT_RANK && t < 160) cvals[t - DT_RANK] = v;
  __syncthreads();
  if (t == 0) {
    float s = 0.0f;
#pragma unroll
    for (int j = 0; j < 16; ++j) s += cvals[j] * cvals[j + 16];
    bc[row] = s;
  }
}

// ---------------- row LayerNorm over (p0 + p1 + h) ----------------
__global__ __launch_bounds__(256)
void ln_kernel(const float* __restrict__ p0, const float* __restrict__ p1,
               const float* __restrict__ hh, const float* __restrict__ gamma,
               const float* __restrict__ beta, float* __restrict__ out)
{
  const int row = blockIdx.x, t = threadIdx.x;
  __shared__ float red[4];
  const float4* x0 = (const float4*)(p0 + (size_t)row * N_HIDDEN);
  const float4* x1 = (const float4*)(p1 + (size_t)row * N_HIDDEN);
  const float4* xh = (const float4*)(hh + (size_t)row * N_HIDDEN);
  float4 a, b;
  {
    float4 u = x0[t], v = x1[t], w = xh[t];
    a.x = u.x + v.x + w.x; a.y = u.y + v.y + w.y; a.z = u.z + v.z + w.z; a.w = u.w + v.w + w.w;
    u = x0[t + 256]; v = x1[t + 256]; w = xh[t + 256];
    b.x = u.x + v.x + w.x; b.y = u.y + v.y + w.y; b.z = u.z + v.z + w.z; b.w = u.w + v.w + w.w;
  }
  float s = ((a.x + a.y) + (a.z + a.w)) + ((b.x + b.y) + (b.z + b.w));
#pragma unroll
  for (int m = 32; m; m >>= 1) s += __shfl_xor(s, m);
  if ((t & 63) == 0) red[t >> 6] = s;
  __syncthreads();
  s = (red[0] + red[1]) + (red[2] + red[3]);
  const float mu = s * (1.0f / N_HIDDEN);
  float dx0 = a.x - mu, dx1 = a.y - mu, dx2 = a.z - mu, dx3 = a.w - mu;
  float dy0 = b.x - mu, dy1 = b.y - mu, dy2 = b.z - mu, dy3 = b.w - mu;
  float q = ((dx0 * dx0 + dx1 * dx1) + (dx2 * dx2 + dx3 * dx3)) +
            ((dy0 * dy0 + dy1 * dy1) + (dy2 * dy2 + dy3 * dy3));
  __syncthreads();
#pragma unroll
  for (int m = 32; m; m >>= 1) q += __shfl_xor(q, m);
  if ((t & 63) == 0) red[t >> 6] = q;
  __syncthreads();
  q = (red[0] + red[1]) + (red[2] + red[3]);
  const float inv = rsqrtf(q * (1.0f / N_HIDDEN) + 1e-5f);
  const float4 ga = ((const float4*)gamma)[t], gb = ((const float4*)gamma)[t + 256];
  const float4 ba = ((const float4*)beta)[t], bbv = ((const float4*)beta)[t + 256];
  float4 o0, o1;
  o0.x = dx0 * inv * ga.x + ba.x;
  o0.y = dx1 * inv * ga.y + ba.y;
  o0.z = dx2 * inv * ga.z + ba.z;
  o0.w = dx3 * inv * ga.w + ba.w;
  o1.x = dy0 * inv * gb.x + bbv.x;
  o1.y = dy1 * inv * gb.y + bbv.y;
  o1.z = dy2 * inv * gb.z + bbv.z;
  o1.w = dy3 * inv * gb.w + bbv.w;
  float4* o4 = (float4*)(out + (size_t)row * N_HIDDEN);
  o4[t] = o0;
  o4[t + 256] = o1;
}

// ---------------- launch ----------------
extern "C" void kernel_launch(void* const* d_in, const int* in_sizes, int n_in,
                              void* d_out, int out_size, void* d_ws, size_t ws_size,
                              hipStream_t stream) {
  const float* x     = (const float*)d_in[0];
  const float* h     = (const float*)d_in[1];
  const float* W_in  = (const float*)d_in[2];
  const float* W_st  = (const float*)d_in[3];
  const float* W_xp  = (const float*)d_in[4];
  const float* W_dt  = (const float*)d_in[5];
  const float* b_dt  = (const float*)d_in[6];
  const float* Dv    = (const float*)d_in[8];
  const float* W_out = (const float*)d_in[9];
  const float* gamma = (const float*)d_in[10];
  const float* beta  = (const float*)d_in[11];
  float* out = (float*)d_out;
  (void)in_sizes; (void)n_in; (void)out_size; (void)ws_size;

  char* ws = (char*)d_ws;
  size_t o = 0;
  auto alloc = [&](size_t bytes) { char* p = ws + o; o += bytes; return p; };
  u16* Acat    = (u16*)alloc((size_t)4096 * 3072 * 2);  // [x | h]   (region reused for y)
  u16* Wcat    = (u16*)alloc((size_t)4096 * 3072 * 2);  // [W_in_lo | W_st]
  u16* Wz_bf   = (u16*)alloc((size_t)4096 * 1024 * 2);
  u16* Wxp_bf  = (u16*)alloc((size_t)160 * 4096 * 2);
  u16* Wdt_bf  = (u16*)alloc((size_t)4096 * 128 * 2);
  u16* Wout_bf = (u16*)alloc((size_t)2048 * 4096 * 2);
  u16* xbr_bf  = (u16*)alloc((size_t)4096 * 4096 * 2);  // reused for p0 (f32)
  u16* sz_bf   = (u16*)alloc((size_t)4096 * 4096 * 2);  // reused for p1 (f32)
  float* part  = (float*)alloc((size_t)4 * 4096 * 160 * 4);
  u16* dtlo_bf = (u16*)alloc((size_t)4096 * 128 * 2);
  float* bc    = (float*)alloc((size_t)4096 * 4);
  // overlays (lifetimes are disjoint):
  u16* y_bf = (u16*)Acat;                  // Acat+Wcat dead by then
  float* p0 = (float*)xbr_bf;              // W_out split-K partials, contiguous
  float* p1 = p0 + (size_t)4096 * 2048;

  // ---- single merged convert launch (8 jobs)
  CvtJobs J;
  J.src[0] = x;                           J.dst[0] = Acat;        J.rl4[0] = 256;  J.dstride[0] = 3072;
  J.src[1] = h;                           J.dst[1] = Acat + 1024; J.rl4[1] = 512;  J.dstride[1] = 3072;
  J.src[2] = W_in;                        J.dst[2] = Wcat;        J.rl4[2] = 256;  J.dstride[2] = 3072;
  J.src[3] = W_st;                        J.dst[3] = Wcat + 1024; J.rl4[3] = 512;  J.dstride[3] = 3072;
  J.src[4] = W_in + (size_t)4096 * 1024;  J.dst[4] = Wz_bf;       J.rl4[4] = 256;  J.dstride[4] = 1024;
  J.src[5] = W_xp;                        J.dst[5] = Wxp_bf;      J.rl4[5] = 1024; J.dstride[5] = 4096;
  J.src[6] = W_dt;                        J.dst[6] = Wdt_bf;      J.rl4[6] = 1024; J.dstride[6] = 4096;  // 4096x128 reshaped 128x4096
  J.src[7] = W_out;                       J.dst[7] = Wout_bf;     J.rl4[7] = 1024; J.dstride[7] = 4096;
  const int rows[8] = {4096, 4096, 4096, 4096, 4096, 160, 128, 2048};
  J.cum[0] = 0;
  for (int k = 0; k < 8; ++k) J.cum[k + 1] = J.cum[k] + rows[k];
  cvt_all_kernel<<<J.cum[8], 256, 0, stream>>>(J);

  // x_br = silu([x|h] @ [W_in_lo|W_st]^T)   M=4096,N=4096,K=3072  (16x16 grid, 4x8 rect)
  gemm8<4096, 3072, 3072, 3072, 0, 16, 16, 4, 8><<<dim3(16, 16, 1), 512, 131072, stream>>>(
      Acat, Wcat, nullptr, xbr_bf, 0);
  // sz = silu(x @ W_in_hi^T)                M=4096,N=4096,K=1024
  gemm8<4096, 1024, 3072, 1024, 0, 16, 16, 4, 8><<<dim3(16, 16, 1), 512, 131072, stream>>>(
      Acat, Wz_bf, nullptr, sz_bf, 0);
  // x_dbl split-K partials + reduce -> dt_lo, bc
  gemm_xproj<<<dim3(64, 4), 256, 0, stream>>>(xbr_bf, Wxp_bf, part);
  xdbl_reduce<<<4096, 192, 0, stream>>>(part, dtlo_bf, bc);
  // y = x_br*(softplus(dt_pre+b_dt)*bc + D)*silu(z)   M=4096,N=4096,K=128
  gemm_bt<4096, 128, 128, 2><<<dim3(32, 32), 256, 67584, stream>>>(
      dtlo_bf, Wdt_bf, nullptr, y_bf, b_dt, bc, Dv, xbr_bf, sz_bf);
  // h_new partials: y @ W_out^T, split-K=2  M=4096,N=2048,K=2x2048  (8x16 grid, 4x4 rect)
  gemm8<2048, 2048, 4096, 4096, 1, 8, 16, 4, 4><<<dim3(8, 16, 2), 512, 131072, stream>>>(
      y_bf, Wout_bf, p0, nullptr, (long long)4096 * 2048);
  // LayerNorm(p0 + p1 + h) -> out
  ln_kernel<<<4096, 256, 0, stream>>>(p0, p1, h, gamma, beta, out);
}

// Round 12
// 345.843 us; speedup vs baseline: 1.0985x; 1.0985x over previous
//
#include <hip/hip_runtime.h>
#include <hip/hip_bf16.h>
#include <cstdint>
#include <cstddef>

typedef unsigned short u16;
typedef __bf16 bf16x8 __attribute__((ext_vector_type(8)));
typedef float f32x4 __attribute__((ext_vector_type(4)));

#define B_ROWS 4096
#define N_HIDDEN 2048
#define DT_RANK 128

static __device__ __forceinline__ u16 f2bf(float f) {
  unsigned u = __float_as_uint(f);
  u += 0x7FFFu + ((u >> 16) & 1u);   // RTNE
  return (u16)(u >> 16);
}
static __device__ __forceinline__ float bf2f(u16 b) {
  return __uint_as_float(((unsigned)b) << 16);
}
static __device__ __forceinline__ float siluf(float v) {
  return v / (1.0f + __expf(-v));
}
static __device__ __forceinline__ float softplusf(float v) {
  return v > 15.0f ? v : log1pf(__expf(v));
}
static __device__ __forceinline__ void async16(void* lds, const void* g) {
  __builtin_amdgcn_global_load_lds((const __attribute__((address_space(1))) void*)g,
                                   (__attribute__((address_space(3))) void*)lds, 16, 0, 0);
}

// ---------------- merged f32 -> bf16 convert (all tensors, one launch) ----------------
struct CvtJobs {
  const float* src[8];
  u16* dst[8];
  int rl4[8];      // row length in float4 units
  int dstride[8];  // dst row stride in u16 units
  int cum[9];      // cumulative row counts
};
__global__ __launch_bounds__(256)
void cvt_all_kernel(CvtJobs J) {
  int b = blockIdx.x;
  int job = 0;
#pragma unroll
  for (int k = 1; k < 8; ++k) if (b >= J.cum[k]) job = k;
  const int row = b - J.cum[job];
  const int rl4 = J.rl4[job];
  const float4* s = (const float4*)(J.src[job] + (size_t)row * (rl4 * 4));
  ushort4* d = (ushort4*)(J.dst[job] + (size_t)row * J.dstride[job]);
  for (int c = threadIdx.x; c < rl4; c += blockDim.x) {
    float4 f = s[c];
    ushort4 o;
    o.x = f2bf(f.x); o.y = f2bf(f.y); o.z = f2bf(f.z); o.w = f2bf(f.w);
    d[c] = o;
  }
}

// ================= 256x256 GEMM: single-gate deep pipeline, unrolled buffers =============
// (r10 structure, unchanged — see its ledger. Rect-XCD tiling, quadrant phases,
//  single vmcnt(6) gate per K-tile, literal LDS buffer offsets via unroll-2.)
template <int NN, int KK, int LDA, int LDB, int EPI, int GX, int GY, int RH, int RW>
__global__ __launch_bounds__(512, 1)
void gemm8(const u16* __restrict__ A, const u16* __restrict__ Bw,
           float* __restrict__ outf, u16* __restrict__ outb, long long zstride)
{
  extern __shared__ u16 lds[];
  u16* ldsA = lds;            // 4 slots (buf*2+half) * 8192 u16 = 64 KiB
  u16* ldsB = lds + 32768;    // 64 KiB
  constexpr int NT = KK / 64;
  static_assert(NT >= 4 && (NT % 2) == 0, "schedule assumes even NT >= 4");
  static_assert(GX * GY == 8 * RH * RW, "rect must partition grid over 8 XCDs");
  static_assert(GX % RW == 0 && GY % RH == 0, "rect divides grid");
  constexpr int XCOLS = GX / RW;
  static_assert((GY / RH) * XCOLS == 8, "XCD grid must be 8");

  const int t = threadIdx.x;
  const int lane = t & 63, w = t >> 6;
  const int wr = w >> 2, wc = w & 3;      // wave grid 2M x 4N
  const int r = lane & 15;
  const int q4 = lane >> 4;               // 0..3 (k-quad)

  // ---- rect-XCD tile mapping (bijective; locality-only) ----
  const int bid = blockIdx.y * GX + blockIdx.x;
  const int xcd = bid & 7;
  const int i = bid >> 3;                 // 0..RH*RW-1
  const int xr = xcd / XCOLS, xc = xcd % XCOLS;
  const int m0 = (xr * RH + i / RW) * 256;
  const int n0 = (xc * RW + i % RW) * 256;
  const int koff = blockIdx.z * KK;

  f32x4 acc[2][2][4][2] = {};   // [a][b][fi][g]

  auto stA = [&](int buf, int half, int k0) {
#pragma unroll
    for (int i2 = 0; i2 < 2; ++i2) {
      const int ii = w * 2 + i2;
      const int c = ii * 64 + lane;          // 16B-chunk index in half-tile
      const int row = c >> 3;
      const int ch = (c & 7) ^ (row & 7);    // inverse-swizzled global chunk
      async16(ldsA + (buf * 2 + half) * 8192 + ii * 512,
              A + (size_t)(m0 + half * 128 + row) * LDA + (koff + k0 + ch * 8));
    }
  };
  auto stB = [&](int buf, int half, int k0) {
#pragma unroll
    for (int i2 = 0; i2 < 2; ++i2) {
      const int ii = w * 2 + i2;
      const int c = ii * 64 + lane;
      const int row = c >> 3;
      const int ch = (c & 7) ^ (row & 7);
      async16(ldsB + (buf * 2 + half) * 8192 + ii * 512,
              Bw + (size_t)(n0 + half * 128 + row) * LDB + (koff + k0 + ch * 8));
    }
  };

  // per-lane ds_read base pointers; all reads are base + compile-time offset
  const int rb = r & 7;
  const int s0 = (q4 ^ rb) << 3;                // u16 units, K32-slice 0
  const int s1 = ((4 + q4) ^ rb) << 3;          // K32-slice 1
  const u16* baA0 = ldsA + (wr * 64 + r) * 64 + s0;
  const u16* baA1 = ldsA + (wr * 64 + r) * 64 + s1;
  const u16* baB0 = ldsB + (wc * 32 + r) * 64 + s0;
  const u16* baB1 = ldsB + (wc * 32 + r) * 64 + s1;

  // ---- prologue: tile0 A0,B0,B1,A1 + tile1 A0,B0,B1 ; vmcnt(6) -> tile0 resident
  stA(0, 0, 0); stB(0, 0, 0); stB(0, 1, 0); stA(0, 1, 0);
  stA(1, 0, 64); stB(1, 0, 64); stB(1, 1, 64);
  asm volatile("s_waitcnt vmcnt(6)" ::: "memory");
  __builtin_amdgcn_s_barrier();
  asm volatile("" ::: "memory");

  for (int j0 = 0; j0 < NT; j0 += 2) {
#pragma unroll
    for (int u = 0; u < 2; ++u) {
      const int j = j0 + u;        // buf(j) == u  (j0 even)
      constexpr int SL = 8192;     // u16 per half-slot
      const int CB = u * 2 * SL;   // cur base offset (literal after unroll)
      bf16x8 fa[8], fah[8], fb0v[4], fb1v[4];

      // ======== q0: read fa<-A0(cur) 8, fb0<-B0(cur) 4 ; stage A1(j+1)->nxt ; MFMA Q00
#pragma unroll
      for (int fi = 0; fi < 4; ++fi) {
        fa[fi * 2 + 0] = *(const bf16x8*)(baA0 + CB + fi * 1024);
        fa[fi * 2 + 1] = *(const bf16x8*)(baA1 + CB + fi * 1024);
      }
#pragma unroll
      for (int g = 0; g < 2; ++g) {
        fb0v[g * 2 + 0] = *(const bf16x8*)(baB0 + CB + g * 1024);
        fb0v[g * 2 + 1] = *(const bf16x8*)(baB1 + CB + g * 1024);
      }
      if (j + 1 < NT) stA(u ^ 1, 1, (j + 1) * 64);
      asm volatile("" ::: "memory");
      __builtin_amdgcn_s_barrier();
      asm volatile("s_waitcnt lgkmcnt(0)" ::: "memory");
      __builtin_amdgcn_s_setprio(1);
#pragma unroll
      for (int fi = 0; fi < 4; ++fi)
#pragma unroll
        for (int g = 0; g < 2; ++g) {
          acc[0][0][fi][g] = __builtin_amdgcn_mfma_f32_16x16x32_bf16(fa[fi * 2 + 0], fb0v[g * 2 + 0], acc[0][0][fi][g], 0, 0, 0);
          acc[0][0][fi][g] = __builtin_amdgcn_mfma_f32_16x16x32_bf16(fa[fi * 2 + 1], fb0v[g * 2 + 1], acc[0][0][fi][g], 0, 0, 0);
        }
      __builtin_amdgcn_s_setprio(0);
      asm volatile("" ::: "memory");
      __builtin_amdgcn_s_barrier();
      asm volatile("" ::: "memory");

      // ======== q1: read fb1<-B1(cur) 4 ; stage A0(j+2)->cur ; MFMA Q01
#pragma unroll
      for (int g = 0; g < 2; ++g) {
        fb1v[g * 2 + 0] = *(const bf16x8*)(baB0 + CB + SL + g * 1024);
        fb1v[g * 2 + 1] = *(const bf16x8*)(baB1 + CB + SL + g * 1024);
      }
      if (j + 2 < NT) stA(u, 0, (j + 2) * 64);
      asm volatile("" ::: "memory");
      __builtin_amdgcn_s_barrier();
      asm volatile("s_waitcnt lgkmcnt(0)" ::: "memory");
      __builtin_amdgcn_s_setprio(1);
#pragma unroll
      for (int fi = 0; fi < 4; ++fi)
#pragma unroll
        for (int g = 0; g < 2; ++g) {
          acc[0][1][fi][g] = __builtin_amdgcn_mfma_f32_16x16x32_bf16(fa[fi * 2 + 0], fb1v[g * 2 + 0], acc[0][1][fi][g], 0, 0, 0);
          acc[0][1][fi][g] = __builtin_amdgcn_mfma_f32_16x16x32_bf16(fa[fi * 2 + 1], fb1v[g * 2 + 1], acc[0][1][fi][g], 0, 0, 0);
        }
      __builtin_amdgcn_s_setprio(0);
      asm volatile("" ::: "memory");
      __builtin_amdgcn_s_barrier();
      asm volatile("" ::: "memory");

      // ======== q2: read fah<-A1(cur) 8 ; stage B0(j+2)->cur ; MFMA Q10
#pragma unroll
      for (int fi = 0; fi < 4; ++fi) {
        fah[fi * 2 + 0] = *(const bf16x8*)(baA0 + CB + SL + fi * 1024);
        fah[fi * 2 + 1] = *(const bf16x8*)(baA1 + CB + SL + fi * 1024);
      }
      if (j + 2 < NT) stB(u, 0, (j + 2) * 64);
      asm volatile("" ::: "memory");
      __builtin_amdgcn_s_barrier();
      asm volatile("s_waitcnt lgkmcnt(0)" ::: "memory");
      __builtin_amdgcn_s_setprio(1);
#pragma unroll
      for (int fi = 0; fi < 4; ++fi)
#pragma unroll
        for (int g = 0; g < 2; ++g) {
          acc[1][0][fi][g] = __builtin_amdgcn_mfma_f32_16x16x32_bf16(fah[fi * 2 + 0], fb0v[g * 2 + 0], acc[1][0][fi][g], 0, 0, 0);
          acc[1][0][fi][g] = __builtin_amdgcn_mfma_f32_16x16x32_bf16(fah[fi * 2 + 1], fb0v[g * 2 + 1], acc[1][0][fi][g], 0, 0, 0);
        }
      __builtin_amdgcn_s_setprio(0);
      asm volatile("" ::: "memory");
      __builtin_amdgcn_s_barrier();
      asm volatile("" ::: "memory");

      // ======== q3: no reads ; stage B1(j+2)->cur ; MFMA Q11 ; SINGLE GATE ; barrier
      if (j + 2 < NT) stB(u, 1, (j + 2) * 64);
      asm volatile("" ::: "memory");
      __builtin_amdgcn_s_barrier();
      __builtin_amdgcn_s_setprio(1);
#pragma unroll
      for (int fi = 0; fi < 4; ++fi)
#pragma unroll
        for (int g = 0; g < 2; ++g) {
          acc[1][1][fi][g] = __builtin_amdgcn_mfma_f32_16x16x32_bf16(fah[fi * 2 + 0], fb1v[g * 2 + 0], acc[1][1][fi][g], 0, 0, 0);
          acc[1][1][fi][g] = __builtin_amdgcn_mfma_f32_16x16x32_bf16(fah[fi * 2 + 1], fb1v[g * 2 + 1], acc[1][1][fi][g], 0, 0, 0);
        }
      __builtin_amdgcn_s_setprio(0);
      if (j + 2 < NT)      { asm volatile("s_waitcnt vmcnt(6)" ::: "memory"); }
      else if (j + 1 < NT) { asm volatile("s_waitcnt vmcnt(0)" ::: "memory"); }
      asm volatile("" ::: "memory");
      __builtin_amdgcn_s_barrier();
      asm volatile("" ::: "memory");
    }
  }

  // ---- epilogue: C/D 16x16 layout col=lane&15, row=(lane>>4)*4+reg
  float* of = outf ? (outf + (size_t)blockIdx.z * zstride) : nullptr;
#pragma unroll
  for (int a = 0; a < 2; ++a)
#pragma unroll
    for (int b = 0; b < 2; ++b)
#pragma unroll
      for (int fi = 0; fi < 4; ++fi)
#pragma unroll
        for (int g = 0; g < 2; ++g)
#pragma unroll
          for (int tt = 0; tt < 4; ++tt) {
            const int grow = m0 + a * 128 + wr * 64 + fi * 16 + q4 * 4 + tt;
            const int gcol = n0 + b * 128 + wc * 32 + g * 16 + r;
            const float v = acc[a][b][fi][g][tt];
            if constexpr (EPI == 0) {
              outb[(size_t)grow * NN + gcol] = f2bf(siluf(v));
            } else {
              of[(size_t)grow * NN + gcol] = v;
            }
          }
}

// ---------------- 128x128 2-phase GEMM (K=128 y-GEMM, coalesced transpose epilogue) ------
// EPI=2: acc -> LDS f32 image [128][128] (aliases the K-loop buffers; WAR-safe via the
// K-loop's final barrier), then half-wave h=t>>5 owns rows {h,h+8,...}, lane32=t&31 owns
// 4 consecutive cols at lane32*4 -> per half-wave instruction 32x8B = 256B CONTIGUOUS
// xaux/saux loads + outb stores (lane-contiguous, not thread-contiguous — r11's bug).
template <int NN, int KK, int LDA, int EPI>
__global__ __launch_bounds__(256)
void gemm_bt(const u16* __restrict__ A, const u16* __restrict__ Bw,
             float* __restrict__ outf, u16* __restrict__ outb,
             const float* __restrict__ aux1, const float* __restrict__ aux2,
             const float* __restrict__ aux3,
             const u16* __restrict__ xaux, const u16* __restrict__ saux)
{
  constexpr int BM = 128, BK = 64;
  extern __shared__ u16 sm[];
  u16* As = sm;                 // [2][BM*BK] = 16384 u16
  u16* Bs = sm + 2 * BM * BK;   // [2][BM*BK]
  const int t = threadIdx.x;
  const int lane = t & 63, w = t >> 6;
  const int m0 = blockIdx.y * BM, n0 = blockIdx.x * BM;
  const int mw = (w >> 1) * 64, nw = (w & 1) * 64;
  const int r = lane & 15;
  const int kq = (lane >> 4) * 8;

  f32x4 acc[4][4] = {};

  auto stage = [&](int buf, int k0) {
#pragma unroll
    for (int i = 0; i < 4; ++i) {
      const int slot0 = (w * 4 + i) * 64;
      const int s = slot0 + lane;
      const int row = s >> 3, cs = (s & 7) * 8;
      async16(As + buf * BM * BK + slot0 * 8, A + (size_t)(m0 + row) * LDA + k0 + cs);
      async16(Bs + buf * BM * BK + slot0 * 8, Bw + (size_t)(n0 + row) * KK + k0 + cs);
    }
  };

  stage(0, 0);
  asm volatile("s_waitcnt vmcnt(0)" ::: "memory");
  __syncthreads();
  int cur = 0;

  for (int k0 = 0; k0 < KK; k0 += BK) {
    if (k0 + BK < KK) stage(cur ^ 1, k0 + BK);
#pragma unroll
    for (int kk = 0; kk < BK; kk += 32) {
      bf16x8 af[4], bb[4];
#pragma unroll
      for (int f = 0; f < 4; ++f)
        af[f] = *(const bf16x8*)(As + cur * BM * BK + (mw + f * 16 + r) * BK + kk + kq);
#pragma unroll
      for (int f = 0; f < 4; ++f)
        bb[f] = *(const bf16x8*)(Bs + cur * BM * BK + (nw + f * 16 + r) * BK + kk + kq);
#pragma unroll
      for (int fm = 0; fm < 4; ++fm)
#pragma unroll
        for (int fn = 0; fn < 4; ++fn)
          acc[fm][fn] = __builtin_amdgcn_mfma_f32_16x16x32_bf16(af[fm], bb[fn], acc[fm][fn], 0, 0, 0);
    }
    asm volatile("s_waitcnt vmcnt(0)" ::: "memory");
    __syncthreads();
    cur ^= 1;
  }

  const int rr = (lane >> 4) * 4;
  const int cc = lane & 15;
  if constexpr (EPI == 2) {
    // transpose acc through LDS (K-loop LDS reads all retired by the final barrier)
    float* fs = (float*)sm;     // 128 x 128 f32 = 65536 B (exactly the K-loop buffers)
#pragma unroll
    for (int fm = 0; fm < 4; ++fm)
#pragma unroll
      for (int fn = 0; fn < 4; ++fn)
#pragma unroll
        for (int tt = 0; tt < 4; ++tt)
          fs[(mw + fm * 16 + rr + tt) * 128 + (nw + fn * 16 + cc)] = acc[fm][fn][tt];
    __syncthreads();
    const int h8 = t >> 5;          // half-wave id 0..7
    const int c4 = (t & 31) * 4;    // 4 consecutive cols per lane
#pragma unroll
    for (int rr2 = 0; rr2 < 16; ++rr2) {
      const int row = rr2 * 8 + h8;
      const size_t grow = (size_t)(m0 + row);
      const int col = n0 + c4;
      const float bcv = aux2[grow];
      float4 v  = *(const float4*)&fs[row * 128 + c4];
      float4 bd = *(const float4*)&aux1[col];
      float4 Dd = *(const float4*)&aux3[col];
      ushort4 xa = *(const ushort4*)(xaux + grow * NN + col);
      ushort4 sa = *(const ushort4*)(saux + grow * NN + col);
      ushort4 oo;
      oo.x = f2bf(bf2f(xa.x) * (softplusf(v.x + bd.x) * bcv + Dd.x) * bf2f(sa.x));
      oo.y = f2bf(bf2f(xa.y) * (softplusf(v.y + bd.y) * bcv + Dd.y) * bf2f(sa.y));
      oo.z = f2bf(bf2f(xa.z) * (softplusf(v.z + bd.z) * bcv + Dd.z) * bf2f(sa.z));
      oo.w = f2bf(bf2f(xa.w) * (softplusf(v.w + bd.w) * bcv + Dd.w) * bf2f(sa.w));
      *(ushort4*)(outb + grow * NN + col) = oo;
    }
  } else {
#pragma unroll
    for (int fm = 0; fm < 4; ++fm) {
#pragma unroll
      for (int fn = 0; fn < 4; ++fn) {
#pragma unroll
        for (int tt = 0; tt < 4; ++tt) {
          const int grow = m0 + mw + fm * 16 + rr + tt;
          const int gcol = n0 + nw + fn * 16 + cc;
          outf[(size_t)grow * NN + gcol] = acc[fm][fn][tt];
        }
      }
    }
  }
}

// ---------------- skinny GEMM: part[kz] = xbr @ Wxp^T over K-chunk ----------------
__global__ __launch_bounds__(256)
void gemm_xproj(const u16* __restrict__ A, const u16* __restrict__ Bw,
                float* __restrict__ part)
{
  constexpr int BK = 64;
  __shared__ alignas(16) u16 As[64 * BK];
  __shared__ alignas(16) u16 Bs[160 * BK];
  const int t = threadIdx.x, lane = t & 63, w = t >> 6;
  const int m0 = blockIdx.x * 64;
  const int kz = blockIdx.y;
  const int r = lane & 15, kq = (lane >> 4) * 8;
  f32x4 acc[10] = {};
  for (int kt = 0; kt < 1024; kt += BK) {
    const int k0 = kz * 1024 + kt;
#pragma unroll
    for (int i = 0; i < 2; ++i) {
      const int slot0 = (w * 2 + i) * 64;
      const int s = slot0 + lane;
      async16(As + slot0 * 8, A + (size_t)(m0 + (s >> 3)) * 4096 + k0 + (s & 7) * 8);
    }
#pragma unroll
    for (int i = 0; i < 5; ++i) {
      const int slot0 = (w * 5 + i) * 64;
      const int s = slot0 + lane;
      async16(Bs + slot0 * 8, Bw + (size_t)(s >> 3) * 4096 + k0 + (s & 7) * 8);
    }
    asm volatile("s_waitcnt vmcnt(0)" ::: "memory");
    __syncthreads();
#pragma unroll
    for (int kk = 0; kk < BK; kk += 32) {
      bf16x8 af = *(const bf16x8*)(As + (w * 16 + r) * BK + kk + kq);
#pragma unroll
      for (int fn = 0; fn < 10; ++fn) {
        bf16x8 bb = *(const bf16x8*)(Bs + (fn * 16 + r) * BK + kk + kq);
        acc[fn] = __builtin_amdgcn_mfma_f32_16x16x32_bf16(af, bb, acc[fn], 0, 0, 0);
      }
    }
    __syncthreads();
  }
  float* o = part + (size_t)kz * B_ROWS * 160;
  const int rr = (lane >> 4) * 4, cc = lane & 15;
#pragma unroll
  for (int fn = 0; fn < 10; ++fn)
#pragma unroll
    for (int tt = 0; tt < 4; ++tt)
      o[(size_t)(m0 + w * 16 + rr + tt) * 160 + fn * 16 + cc] = acc[fn][tt];
}

// ---------------- reduce split-K partials -> dt_lo (bf16) + bc ----------------
__global__ __launch_bounds__(192)
void xdbl_reduce(const float* __restrict__ part, u16* __restrict__ dtlo,
                 float* __restrict__ bc)
{
  const int row = blockIdx.x, t = threadIdx.x;
  __shared__ float cvals[32];
  float v = 0.0f;
  if (t < 160) {
    const float* p = part + (size_t)row * 160 + t;
#pragma unroll
    for (int z = 0; z < 4; ++z) v += p[(size_t)z * B_ROWS * 160];
  }
  if (t < DT_RANK) dtlo[(size_t)row * DT_RANK + t] = f2bf(v);
  if (t >= DT_RANK && t < 160) cvals[t - DT_RANK] = v;
  __syncthreads();
  if (t == 0) {
    float s = 0.0f;
#pragma unroll
    for (int j = 0; j < 16; ++j) s += cvals[j] * cvals[j + 16];
    bc[row] = s;
  }
}

// ---------------- row LayerNorm over (p0 + p1 + h) ----------------
__global__ __launch_bounds__(256)
void ln_kernel(const float* __restrict__ p0, const float* __restrict__ p1,
               const float* __restrict__ hh, const float* __restrict__ gamma,
               const float* __restrict__ beta, float* __restrict__ out)
{
  const int row = blockIdx.x, t = threadIdx.x;
  __shared__ float red[4];
  const float4* x0 = (const float4*)(p0 + (size_t)row * N_HIDDEN);
  const float4* x1 = (const float4*)(p1 + (size_t)row * N_HIDDEN);
  const float4* xh = (const float4*)(hh + (size_t)row * N_HIDDEN);
  float4 a, b;
  {
    float4 u = x0[t], v = x1[t], w = xh[t];
    a.x = u.x + v.x + w.x; a.y = u.y + v.y + w.y; a.z = u.z + v.z + w.z; a.w = u.w + v.w + w.w;
    u = x0[t + 256]; v = x1[t + 256]; w = xh[t + 256];
    b.x = u.x + v.x + w.x; b.y = u.y + v.y + w.y; b.z = u.z + v.z + w.z; b.w = u.w + v.w + w.w;
  }
  float s = ((a.x + a.y) + (a.z + a.w)) + ((b.x + b.y) + (b.z + b.w));
#pragma unroll
  for (int m = 32; m; m >>= 1) s += __shfl_xor(s, m);
  if ((t & 63) == 0) red[t >> 6] = s;
  __syncthreads();
  s = (red[0] + red[1]) + (red[2] + red[3]);
  const float mu = s * (1.0f / N_HIDDEN);
  float dx0 = a.x - mu, dx1 = a.y - mu, dx2 = a.z - mu, dx3 = a.w - mu;
  float dy0 = b.x - mu, dy1 = b.y - mu, dy2 = b.z - mu, dy3 = b.w - mu;
  float q = ((dx0 * dx0 + dx1 * dx1) + (dx2 * dx2 + dx3 * dx3)) +
            ((dy0 * dy0 + dy1 * dy1) + (dy2 * dy2 + dy3 * dy3));
  __syncthreads();
#pragma unroll
  for (int m = 32; m; m >>= 1) q += __shfl_xor(q, m);
  if ((t & 63) == 0) red[t >> 6] = q;
  __syncthreads();
  q = (red[0] + red[1]) + (red[2] + red[3]);
  const float inv = rsqrtf(q * (1.0f / N_HIDDEN) + 1e-5f);
  const float4 ga = ((const float4*)gamma)[t], gb = ((const float4*)gamma)[t + 256];
  const float4 ba = ((const float4*)beta)[t], bbv = ((const float4*)beta)[t + 256];
  float4 o0, o1;
  o0.x = dx0 * inv * ga.x + ba.x;
  o0.y = dx1 * inv * ga.y + ba.y;
  o0.z = dx2 * inv * ga.z + ba.z;
  o0.w = dx3 * inv * ga.w + ba.w;
  o1.x = dy0 * inv * gb.x + bbv.x;
  o1.y = dy1 * inv * gb.y + bbv.y;
  o1.z = dy2 * inv * gb.z + bbv.z;
  o1.w = dy3 * inv * gb.w + bbv.w;
  float4* o4 = (float4*)(out + (size_t)row * N_HIDDEN);
  o4[t] = o0;
  o4[t + 256] = o1;
}

// ---------------- launch ----------------
extern "C" void kernel_launch(void* const* d_in, const int* in_sizes, int n_in,
                              void* d_out, int out_size, void* d_ws, size_t ws_size,
                              hipStream_t stream) {
  const float* x     = (const float*)d_in[0];
  const float* h     = (const float*)d_in[1];
  const float* W_in  = (const float*)d_in[2];
  const float* W_st  = (const float*)d_in[3];
  const float* W_xp  = (const float*)d_in[4];
  const float* W_dt  = (const float*)d_in[5];
  const float* b_dt  = (const float*)d_in[6];
  const float* Dv    = (const float*)d_in[8];
  const float* W_out = (const float*)d_in[9];
  const float* gamma = (const float*)d_in[10];
  const float* beta  = (const float*)d_in[11];
  float* out = (float*)d_out;
  (void)in_sizes; (void)n_in; (void)out_size; (void)ws_size;

  char* ws = (char*)d_ws;
  size_t o = 0;
  auto alloc = [&](size_t bytes) { char* p = ws + o; o += bytes; return p; };
  u16* Acat    = (u16*)alloc((size_t)4096 * 3072 * 2);  // [x | h]   (region reused for y)
  u16* Wcat    = (u16*)alloc((size_t)4096 * 3072 * 2);  // [W_in_lo | W_st]
  u16* Wz_bf   = (u16*)alloc((size_t)4096 * 1024 * 2);
  u16* Wxp_bf  = (u16*)alloc((size_t)160 * 4096 * 2);
  u16* Wdt_bf  = (u16*)alloc((size_t)4096 * 128 * 2);
  u16* Wout_bf = (u16*)alloc((size_t)2048 * 4096 * 2);
  u16* xbr_bf  = (u16*)alloc((size_t)4096 * 4096 * 2);  // reused for p0 (f32)
  u16* sz_bf   = (u16*)alloc((size_t)4096 * 4096 * 2);  // reused for p1 (f32)
  float* part  = (float*)alloc((size_t)4 * 4096 * 160 * 4);
  u16* dtlo_bf = (u16*)alloc((size_t)4096 * 128 * 2);
  float* bc    = (float*)alloc((size_t)4096 * 4);
  // overlays (lifetimes are disjoint):
  u16* y_bf = (u16*)Acat;                  // Acat+Wcat dead by then
  float* p0 = (float*)xbr_bf;              // W_out split-K partials, contiguous
  float* p1 = p0 + (size_t)4096 * 2048;

  // ---- single merged convert launch (8 jobs)
  CvtJobs J;
  J.src[0] = x;                           J.dst[0] = Acat;        J.rl4[0] = 256;  J.dstride[0] = 3072;
  J.src[1] = h;                           J.dst[1] = Acat + 1024; J.rl4[1] = 512;  J.dstride[1] = 3072;
  J.src[2] = W_in;                        J.dst[2] = Wcat;        J.rl4[2] = 256;  J.dstride[2] = 3072;
  J.src[3] = W_st;                        J.dst[3] = Wcat + 1024; J.rl4[3] = 512;  J.dstride[3] = 3072;
  J.src[4] = W_in + (size_t)4096 * 1024;  J.dst[4] = Wz_bf;       J.rl4[4] = 256;  J.dstride[4] = 1024;
  J.src[5] = W_xp;                        J.dst[5] = Wxp_bf;      J.rl4[5] = 1024; J.dstride[5] = 4096;
  J.src[6] = W_dt;                        J.dst[6] = Wdt_bf;      J.rl4[6] = 1024; J.dstride[6] = 4096;  // 4096x128 reshaped 128x4096
  J.src[7] = W_out;                       J.dst[7] = Wout_bf;     J.rl4[7] = 1024; J.dstride[7] = 4096;
  const int rows[8] = {4096, 4096, 4096, 4096, 4096, 160, 128, 2048};
  J.cum[0] = 0;
  for (int k = 0; k < 8; ++k) J.cum[k + 1] = J.cum[k] + rows[k];
  cvt_all_kernel<<<J.cum[8], 256, 0, stream>>>(J);

  // x_br = silu([x|h] @ [W_in_lo|W_st]^T)   M=4096,N=4096,K=3072  (16x16 grid, 4x8 rect)
  gemm8<4096, 3072, 3072, 3072, 0, 16, 16, 4, 8><<<dim3(16, 16, 1), 512, 131072, stream>>>(
      Acat, Wcat, nullptr, xbr_bf, 0);
  // sz = silu(x @ W_in_hi^T)                M=4096,N=4096,K=1024
  gemm8<4096, 1024, 3072, 1024, 0, 16, 16, 4, 8><<<dim3(16, 16, 1), 512, 131072, stream>>>(
      Acat, Wz_bf, nullptr, sz_bf, 0);
  // x_dbl split-K partials + reduce -> dt_lo, bc
  gemm_xproj<<<dim3(64, 4), 256, 0, stream>>>(xbr_bf, Wxp_bf, part);
  xdbl_reduce<<<4096, 192, 0, stream>>>(part, dtlo_bf, bc);
  // y = x_br*(softplus(dt_pre+b_dt)*bc + D)*silu(z)   M=4096,N=4096,K=128
  gemm_bt<4096, 128, 128, 2><<<dim3(32, 32), 256, 65536, stream>>>(
      dtlo_bf, Wdt_bf, nullptr, y_bf, b_dt, bc, Dv, xbr_bf, sz_bf);
  // h_new partials: y @ W_out^T, split-K=2  M=4096,N=2048,K=2x2048  (8x16 grid, 4x4 rect)
  gemm8<2048, 2048, 4096, 4096, 1, 8, 16, 4, 4><<<dim3(8, 16, 2), 512, 131072, stream>>>(
      y_bf, Wout_bf, p0, nullptr, (long long)4096 * 2048);
  // LayerNorm(p0 + p1 + h) -> out
  ln_kernel<<<4096, 256, 0, stream>>>(p0, p1, h, gamma, beta, out);
}